// Round 10
// baseline (371.409 us; speedup 1.0000x reference)
//
#include <hip/hip_runtime.h>
#include <hip/hip_fp16.h>

typedef _Float16 h4t __attribute__((ext_vector_type(4)));
typedef _Float16 h8t __attribute__((ext_vector_type(8)));
typedef float f4t __attribute__((ext_vector_type(4)));

static constexpr int T = 512;
static constexpr int B = 4096;

__device__ __forceinline__ float frcp_(float x) { return __builtin_amdgcn_rcpf(x); }
__device__ __forceinline__ float sig_(float x) { return frcp_(1.0f + __expf(-x)); }
__device__ __forceinline__ float tanh_(float x) { return 1.0f - 2.0f * frcp_(1.0f + __expf(2.0f * x)); }

// pack 4 floats -> h4t via two v_cvt_pkrtz
__device__ __forceinline__ h4t pack4_(float a, float b, float c, float d) {
    auto p0 = __builtin_amdgcn_cvt_pkrtz(a, b);   // __fp16 x2
    auto p1 = __builtin_amdgcn_cvt_pkrtz(c, d);
    union { struct { decltype(p0) a, b; } p; h4t h; } cv;
    cv.p.a = p0; cv.p.b = p1;
    return cv.h;
}

// ------------- Kernel 1: layer-0 fwd+bwd scans via MFMA, 16 seqs/wave ------
// gates[48x16] = Whh[48x16] @ h[16x16] (3x mfma_16x16x16f16), with the
// rank-1 x-part folded into the C operand: C[i] = x_c*wx[4g+i] + bias.
// D-layout(row=4g+i,col=c) == B-layout(k=4g+i,col=c) -> h feedback is two
// in-lane v_cvt_pkrtz. No LDS. dir = blockIdx.x>>8 (0:fwd, 1:bwd).
__global__ void __launch_bounds__(64, 1) k_l0m(
    const float* __restrict__ x,      // [B,T]
    const float* __restrict__ Wf, const float* __restrict__ Uf,
    const float* __restrict__ bif, const float* __restrict__ bhf,
    const float* __restrict__ Wb, const float* __restrict__ Ub,
    const float* __restrict__ bib, const float* __restrict__ bhb,
    __half* __restrict__ y0f,         // [T,B,16] f16
    __half* __restrict__ y0b)         // [T,B,16] f16
{
    const int lane = threadIdx.x & 63;
    const int c = lane & 15;          // seq col (B/D); weight row for A
    const int g = lane >> 4;          // k-group / row-group
    const int dir = blockIdx.x >> 8;
    const int b = (blockIdx.x & 255) * 16 + c;

    const float* Wih = dir ? Wb : Wf;
    const float* Whh = dir ? Ub : Uf;
    const float* bih = dir ? bib : bif;
    const float* bhh = dir ? bhb : bhf;

    // A fragments (hh tiles r/z/n): A[m=c][k=4g+e]
    h4t Ahr, Ahz, Ahn;
#pragma unroll
    for (int e = 0; e < 4; ++e) {
        Ahr[e] = (_Float16)Whh[(size_t)c * 16 + 4 * g + e];
        Ahz[e] = (_Float16)Whh[(size_t)(16 + c) * 16 + 4 * g + e];
        Ahn[e] = (_Float16)Whh[(size_t)(32 + c) * 16 + 4 * g + e];
    }
    // per-row x-weights / biases (row = 4g+i)
    float wxr[4], wxz[4], wxn[4], br_[4], bz_[4], bin_[4];
    f4t Chn;
#pragma unroll
    for (int i = 0; i < 4; ++i) {
        const int row = 4 * g + i;
        wxr[i] = Wih[row];
        wxz[i] = Wih[16 + row];
        wxn[i] = Wih[32 + row];
        br_[i] = bih[row] + bhh[row];
        bz_[i] = bih[16 + row] + bhh[16 + row];
        bin_[i] = bih[32 + row];
        Chn[i] = bhh[32 + row];
    }

    const int t0   = dir ? (T - 1) : 0;
    const int step = dir ? -1 : 1;
    const float* xp = x + (size_t)b * T + t0;
    __half* yp = (dir ? y0b : y0f) + ((size_t)t0 * B + b) * 16 + 4 * g;
    const ptrdiff_t ystep = (ptrdiff_t)step * B * 16;

    float xa = xp[0];
    float xb1 = xp[step];
    const float* xq = xp + 2 * step;   // 2-deep prefetch
    float h[4] = {0.0f, 0.0f, 0.0f, 0.0f};
    h4t Bh = {};                        // h(-1) = 0 (f16 feedback)

    for (int it = 0; it < T; ++it) {
        float x2 = *xq;
        if (it < T - 3) xq += step;
        f4t Cr, Cz;
#pragma unroll
        for (int i = 0; i < 4; ++i) {
            Cr[i] = fmaf(xa, wxr[i], br_[i]);
            Cz[i] = fmaf(xa, wxz[i], bz_[i]);
        }
        f4t Er = __builtin_amdgcn_mfma_f32_16x16x16f16(Ahr, Bh, Cr, 0, 0, 0);
        f4t Ez = __builtin_amdgcn_mfma_f32_16x16x16f16(Ahz, Bh, Cz, 0, 0, 0);
        f4t En = __builtin_amdgcn_mfma_f32_16x16x16f16(Ahn, Bh, Chn, 0, 0, 0);
#pragma unroll
        for (int i = 0; i < 4; ++i) {
            float r = sig_(Er[i]);
            float z = sig_(Ez[i]);
            float n = tanh_(fmaf(r, En[i], fmaf(xa, wxn[i], bin_[i])));
            h[i] = fmaf(z, h[i] - n, n);          // (1-z)n + z h
        }
        Bh = pack4_(h[0], h[1], h[2], h[3]);
        *reinterpret_cast<h4t*>(yp) = Bh;         // 8B coalesced store
        yp += ystep;
        xa = xb1; xb1 = x2;
    }
}

// ---------------- Kernel 2: layer-1 via MFMA, 16 sequences per wave --------
// (unchanged from round 9 — proven)
__global__ void __launch_bounds__(64, 1) k_l1m(
    const __half* __restrict__ y0f, const __half* __restrict__ y0b,
    const float* __restrict__ Wih1, const float* __restrict__ Whh1,
    const float* __restrict__ bih1, const float* __restrict__ bhh1,
    const float* __restrict__ Wih1b,
    const float* __restrict__ bih1b, const float* __restrict__ bhh1b,
    float* __restrict__ out)              // [B,32]
{
    const int lane = threadIdx.x & 63;
    const int c = lane & 15;
    const int g = lane >> 4;
    const int b = blockIdx.x * 16 + c;

    h8t Air, Aiz, Ain;
    {
        const float* pr = Wih1 + (size_t)c * 32 + 8 * g;
        const float* pz = Wih1 + (size_t)(16 + c) * 32 + 8 * g;
        const float* pn = Wih1 + (size_t)(32 + c) * 32 + 8 * g;
#pragma unroll
        for (int e = 0; e < 8; ++e) {
            Air[e] = (_Float16)pr[e];
            Aiz[e] = (_Float16)pz[e];
            Ain[e] = (_Float16)pn[e];
        }
    }
    h4t Ahr, Ahz, Ahn;
    {
        const float* pr = Whh1 + (size_t)c * 16 + 4 * g;
        const float* pz = Whh1 + (size_t)(16 + c) * 16 + 4 * g;
        const float* pn = Whh1 + (size_t)(32 + c) * 16 + 4 * g;
#pragma unroll
        for (int e = 0; e < 4; ++e) {
            Ahr[e] = (_Float16)pr[e];
            Ahz[e] = (_Float16)pz[e];
            Ahn[e] = (_Float16)pn[e];
        }
    }
    f4t Crb, Czb, Cnb, Chn, Z4;
#pragma unroll
    for (int i = 0; i < 4; ++i) {
        const int row = 4 * g + i;
        Crb[i] = bih1[row] + bhh1[row];
        Czb[i] = bih1[16 + row] + bhh1[16 + row];
        Cnb[i] = bih1[32 + row];
        Chn[i] = bhh1[32 + row];
        Z4[i]  = 0.0f;
    }

    const __half* ysrc = (g < 2) ? y0f : y0b;
    const uint4* yp = reinterpret_cast<const uint4*>(
        ysrc + (size_t)b * 16 + (size_t)(g & 1) * 8);
    const size_t ystr = (size_t)B * 2;

    uint4 ya  = yp[0];
    uint4 yb4 = yp[ystr];

    float h[4] = {0.0f, 0.0f, 0.0f, 0.0f};
    h4t Bh = {};

    for (int it = 0; it < T; ++it) {
        const size_t tn = (it < T - 2) ? (size_t)(it + 2) : (size_t)(T - 1);
        uint4 yc = yp[tn * ystr];
        h8t By;
        { union { uint4 u; h8t h; } cv; cv.u = ya; By = cv.h; }
        f4t Dr = __builtin_amdgcn_mfma_f32_16x16x32_f16(Air, By, Crb, 0, 0, 0);
        f4t Dz = __builtin_amdgcn_mfma_f32_16x16x32_f16(Aiz, By, Czb, 0, 0, 0);
        f4t Dn = __builtin_amdgcn_mfma_f32_16x16x32_f16(Ain, By, Cnb, 0, 0, 0);
        f4t Er = __builtin_amdgcn_mfma_f32_16x16x16f16(Ahr, Bh, Z4, 0, 0, 0);
        f4t Ez = __builtin_amdgcn_mfma_f32_16x16x16f16(Ahz, Bh, Z4, 0, 0, 0);
        f4t En = __builtin_amdgcn_mfma_f32_16x16x16f16(Ahn, Bh, Chn, 0, 0, 0);
#pragma unroll
        for (int i = 0; i < 4; ++i) {
            float r = sig_(Dr[i] + Er[i]);
            float z = sig_(Dz[i] + Ez[i]);
            float n = tanh_(fmaf(r, En[i], Dn[i]));
            h[i] = fmaf(z, h[i] - n, n);
        }
        Bh = pack4_(h[0], h[1], h[2], h[3]);
        ya = yb4; yb4 = yc;
    }

#pragma unroll
    for (int i = 0; i < 4; ++i)
        out[(size_t)b * 32 + 4 * g + i] = h[i];

    // ---- L1 backward single step at t=T-1 from h=0; ya = y(T-1)
    h8t Abr, Abz, Abn;
    {
        const float* pr = Wih1b + (size_t)c * 32 + 8 * g;
        const float* pz = Wih1b + (size_t)(16 + c) * 32 + 8 * g;
        const float* pn = Wih1b + (size_t)(32 + c) * 32 + 8 * g;
#pragma unroll
        for (int e = 0; e < 8; ++e) {
            Abr[e] = (_Float16)pr[e];
            Abz[e] = (_Float16)pz[e];
            Abn[e] = (_Float16)pn[e];
        }
    }
    f4t Cbr, Cbz, Cbn;
    float ghn[4];
#pragma unroll
    for (int i = 0; i < 4; ++i) {
        const int row = 4 * g + i;
        Cbr[i] = bih1b[row] + bhh1b[row];
        Cbz[i] = bih1b[16 + row] + bhh1b[16 + row];
        Cbn[i] = bih1b[32 + row];
        ghn[i] = bhh1b[32 + row];
    }
    h8t By;
    { union { uint4 u; h8t h; } cv; cv.u = ya; By = cv.h; }
    f4t Dr = __builtin_amdgcn_mfma_f32_16x16x32_f16(Abr, By, Cbr, 0, 0, 0);
    f4t Dz = __builtin_amdgcn_mfma_f32_16x16x32_f16(Abz, By, Cbz, 0, 0, 0);
    f4t Dn = __builtin_amdgcn_mfma_f32_16x16x32_f16(Abn, By, Cbn, 0, 0, 0);
#pragma unroll
    for (int i = 0; i < 4; ++i) {
        float r = sig_(Dr[i]);
        float z = sig_(Dz[i]);
        float n = tanh_(fmaf(r, ghn[i], Dn[i]));
        out[(size_t)b * 32 + 16 + 4 * g + i] = (1.0f - z) * n;
    }
}

extern "C" void kernel_launch(void* const* d_in, const int* in_sizes, int n_in,
                              void* d_out, int out_size, void* d_ws, size_t ws_size,
                              hipStream_t stream) {
    const float* x     = (const float*)d_in[0];
    const float* Wih0f = (const float*)d_in[1];
    const float* Whh0f = (const float*)d_in[2];
    const float* bih0f = (const float*)d_in[3];
    const float* bhh0f = (const float*)d_in[4];
    const float* Wih0b = (const float*)d_in[5];
    const float* Whh0b = (const float*)d_in[6];
    const float* bih0b = (const float*)d_in[7];
    const float* bhh0b = (const float*)d_in[8];
    const float* Wih1f = (const float*)d_in[9];
    const float* Whh1f = (const float*)d_in[10];
    const float* bih1f = (const float*)d_in[11];
    const float* bhh1f = (const float*)d_in[12];
    const float* Wih1b = (const float*)d_in[13];
    const float* bih1b = (const float*)d_in[15];
    const float* bhh1b = (const float*)d_in[16];

    __half* y0f = (__half*)d_ws;                   // [T,B,16] f16 = 64 MiB
    __half* y0b = y0f + (size_t)T * B * 16;        // [T,B,16] f16 = 64 MiB
    float* out = (float*)d_out;

    // K1: 256 fwd blocks + 256 bwd blocks, 1 wave each.
    hipLaunchKernelGGL(k_l0m, dim3(512), dim3(64), 0, stream,
                       x, Wih0f, Whh0f, bih0f, bhh0f,
                       Wih0b, Whh0b, bih0b, bhh0b, y0f, y0b);
    // K2: 4096 seqs, 16 per wave -> 256 blocks.
    hipLaunchKernelGGL(k_l1m, dim3(B / 16), dim3(64), 0, stream,
                       y0f, y0b, Wih1f, Whh1f, bih1f, bhh1f,
                       Wih1b, bih1b, bhh1b, out);
}

// Round 11
// 285.029 us; speedup vs baseline: 1.3031x; 1.3031x over previous
//
#include <hip/hip_runtime.h>
#include <hip/hip_fp16.h>

typedef float v2f __attribute__((ext_vector_type(2)));
typedef _Float16 h4t __attribute__((ext_vector_type(4)));
typedef _Float16 h8t __attribute__((ext_vector_type(8)));
typedef float f4t __attribute__((ext_vector_type(4)));

static constexpr int T = 512;
static constexpr int B = 4096;

__device__ __forceinline__ float frcp_(float x) { return __builtin_amdgcn_rcpf(x); }
__device__ __forceinline__ float sig_(float x) { return frcp_(1.0f + __expf(-x)); }
__device__ __forceinline__ float tanh_(float x) { return 1.0f - 2.0f * frcp_(1.0f + __expf(2.0f * x)); }

// Compiler fence + scheduling barrier (same-wave LDS ops are in-order in HW).
#define WAVE_SYNC() do { asm volatile("" ::: "memory"); \
                         __builtin_amdgcn_wave_barrier(); \
                         asm volatile("" ::: "memory"); } while (0)

// pack 4 floats -> h4t via two v_cvt_pkrtz
__device__ __forceinline__ h4t pack4_(float a, float b, float c, float d) {
    auto p0 = __builtin_amdgcn_cvt_pkrtz(a, b);   // __fp16 x2
    auto p1 = __builtin_amdgcn_cvt_pkrtz(c, d);
    union { struct { decltype(p0) a, b; } p; h4t h; } cv;
    cv.p.a = p0; cv.p.b = p1;
    return cv.h;
}

// ---------------- Kernel 1: layer-0 forward AND backward scans -------------
// (round-7 scalar version — proven 163 us)
__global__ void __launch_bounds__(256, 2) k_l0(
    const float* __restrict__ x,      // [B,T]
    const float* __restrict__ Wf, const float* __restrict__ Uf,
    const float* __restrict__ bif, const float* __restrict__ bhf,
    const float* __restrict__ Wb, const float* __restrict__ Ub,
    const float* __restrict__ bib, const float* __restrict__ bhb,
    __half* __restrict__ y0f,         // [T,B,16] f16
    __half* __restrict__ y0b)         // [T,B,16] f16
{
    __shared__ float hbuf[256];
    const int tid = threadIdx.x;
    const int j   = tid & 15;
    const int dir = (tid >> 4) & 1;
    const int s   = tid >> 5;
    const int b   = blockIdx.x * 8 + s;
    float* hb = hbuf + (tid >> 4) * 16;

    const float* Wih = dir ? Wb : Wf;
    const float* Whh = dir ? Ub : Uf;
    const float* bih = dir ? bib : bif;
    const float* bhh = dir ? bhb : bhf;

    v2f wr[8], wz[8], wn[8];
    {
        const v2f* pr = reinterpret_cast<const v2f*>(Whh + j * 16);
        const v2f* pz = reinterpret_cast<const v2f*>(Whh + (16 + j) * 16);
        const v2f* pn = reinterpret_cast<const v2f*>(Whh + (32 + j) * 16);
#pragma unroll
        for (int q = 0; q < 8; ++q) { wr[q] = pr[q]; wz[q] = pz[q]; wn[q] = pn[q]; }
    }
    const float wxr  = Wih[j], wxz = Wih[16 + j], wxn = Wih[32 + j];
    const float br   = bih[j] + bhh[j];
    const float bz   = bih[16 + j] + bhh[16 + j];
    const float bin_ = bih[32 + j];
    const float bhn  = bhh[32 + j];

    const int t0   = dir ? (T - 1) : 0;
    const int step = dir ? -1 : 1;
    const float* xp = x + (size_t)b * T + t0;
    __half* yp = (dir ? y0b : y0f) + ((size_t)t0 * B + b) * 16 + j;
    const ptrdiff_t ystep = (ptrdiff_t)step * B * 16;

    hb[j] = 0.0f;
    WAVE_SYNC();

    float xv = xp[0];
    float x1 = xp[step];
    const float* xq = xp + 2 * step;
    float hj = 0.0f;

    for (int it = 0; it < T; ++it) {
        float x2 = *xq;
        if (it < T - 3) xq += step;
        v2f A[8];
#pragma unroll
        for (int q = 0; q < 4; ++q) {
            float4 v = *reinterpret_cast<const float4*>(hb + 4 * q);
            A[2 * q + 0][0] = v.x; A[2 * q + 0][1] = v.y;
            A[2 * q + 1][0] = v.z; A[2 * q + 1][1] = v.w;
        }
        v2f a0 = { fmaf(xv, wxr, br), 0.0f };
        v2f a1 = { fmaf(xv, wxz, bz), 0.0f };
        v2f a2 = { bhn, 0.0f };
#pragma unroll
        for (int q = 0; q < 8; ++q) {
            a0 += wr[q] * A[q];
            a1 += wz[q] * A[q];
            a2 += wn[q] * A[q];
        }
        float ar = a0[0] + a0[1];
        float az = a1[0] + a1[1];
        float hn = a2[0] + a2[1];
        float r = sig_(ar), z = sig_(az);
        float n = tanh_(fmaf(r, hn, fmaf(xv, wxn, bin_)));
        hj = fmaf(z, hj - n, n);
        *yp = __float2half(hj);
        yp += ystep;
        WAVE_SYNC();
        hb[j] = hj;
        WAVE_SYNC();
        xv = x1; x1 = x2;
    }
}

// ---------------- Kernel 2: layer-1 via MFMA, 16 sequences per wave --------
// Same structure as round 9 (verified), but with an 8-deep rotating y
// prefetch buffer: the load issued at step t is consumed at t+8, covering
// HBM latency (~900 cy) at wall ~125 cy/step of slack per stage.
__global__ void __launch_bounds__(64, 1) k_l1m(
    const __half* __restrict__ y0f, const __half* __restrict__ y0b,
    const float* __restrict__ Wih1, const float* __restrict__ Whh1,
    const float* __restrict__ bih1, const float* __restrict__ bhh1,
    const float* __restrict__ Wih1b,
    const float* __restrict__ bih1b, const float* __restrict__ bhh1b,
    float* __restrict__ out)              // [B,32]
{
    const int lane = threadIdx.x & 63;
    const int c = lane & 15;
    const int g = lane >> 4;
    const int b = blockIdx.x * 16 + c;

    h8t Air, Aiz, Ain;
    {
        const float* pr = Wih1 + (size_t)c * 32 + 8 * g;
        const float* pz = Wih1 + (size_t)(16 + c) * 32 + 8 * g;
        const float* pn = Wih1 + (size_t)(32 + c) * 32 + 8 * g;
#pragma unroll
        for (int e = 0; e < 8; ++e) {
            Air[e] = (_Float16)pr[e];
            Aiz[e] = (_Float16)pz[e];
            Ain[e] = (_Float16)pn[e];
        }
    }
    h4t Ahr, Ahz, Ahn;
    {
        const float* pr = Whh1 + (size_t)c * 16 + 4 * g;
        const float* pz = Whh1 + (size_t)(16 + c) * 16 + 4 * g;
        const float* pn = Whh1 + (size_t)(32 + c) * 16 + 4 * g;
#pragma unroll
        for (int e = 0; e < 4; ++e) {
            Ahr[e] = (_Float16)pr[e];
            Ahz[e] = (_Float16)pz[e];
            Ahn[e] = (_Float16)pn[e];
        }
    }
    f4t Crb, Czb, Cnb, Chn, Z4;
#pragma unroll
    for (int i = 0; i < 4; ++i) {
        const int row = 4 * g + i;
        Crb[i] = bih1[row] + bhh1[row];
        Czb[i] = bih1[16 + row] + bhh1[16 + row];
        Cnb[i] = bih1[32 + row];
        Chn[i] = bhh1[32 + row];
        Z4[i]  = 0.0f;
    }

    const __half* ysrc = (g < 2) ? y0f : y0b;
    const uint4* yp = reinterpret_cast<const uint4*>(
        ysrc + (size_t)b * 16 + (size_t)(g & 1) * 8);
    const size_t ystr = (size_t)B * 2;            // uint4 per time step

    // 8-deep rotating prefetch buffer (constant indices under unroll 8)
    uint4 buf[8];
#pragma unroll
    for (int i = 0; i < 8; ++i) buf[i] = yp[(size_t)i * ystr];

    float h[4] = {0.0f, 0.0f, 0.0f, 0.0f};
    h4t Bh = {};

#pragma unroll 8
    for (int it = 0; it < T; ++it) {
        uint4 ya = buf[it & 7];
        const size_t tn = (it + 8 < T) ? (size_t)(it + 8) : (size_t)(T - 1);
        buf[it & 7] = yp[tn * ystr];              // issue load for t+8
        h8t By;
        { union { uint4 u; h8t h; } cv; cv.u = ya; By = cv.h; }
        f4t Dr = __builtin_amdgcn_mfma_f32_16x16x32_f16(Air, By, Crb, 0, 0, 0);
        f4t Dz = __builtin_amdgcn_mfma_f32_16x16x32_f16(Aiz, By, Czb, 0, 0, 0);
        f4t Dn = __builtin_amdgcn_mfma_f32_16x16x32_f16(Ain, By, Cnb, 0, 0, 0);
        f4t Er = __builtin_amdgcn_mfma_f32_16x16x16f16(Ahr, Bh, Z4, 0, 0, 0);
        f4t Ez = __builtin_amdgcn_mfma_f32_16x16x16f16(Ahz, Bh, Z4, 0, 0, 0);
        f4t En = __builtin_amdgcn_mfma_f32_16x16x16f16(Ahn, Bh, Chn, 0, 0, 0);
#pragma unroll
        for (int i = 0; i < 4; ++i) {
            float r = sig_(Dr[i] + Er[i]);
            float z = sig_(Dz[i] + Ez[i]);
            float n = tanh_(fmaf(r, En[i], Dn[i]));
            h[i] = fmaf(z, h[i] - n, n);
        }
        Bh = pack4_(h[0], h[1], h[2], h[3]);
    }

#pragma unroll
    for (int i = 0; i < 4; ++i)
        out[(size_t)b * 32 + 4 * g + i] = h[i];

    // ---- L1 backward single step at t=T-1 from h=0.
    // buf[(T-1)&7] was refilled at it=T-1 with the clamped load y(T-1).
    uint4 yfin = buf[(T - 1) & 7];
    h8t Abr, Abz, Abn;
    {
        const float* pr = Wih1b + (size_t)c * 32 + 8 * g;
        const float* pz = Wih1b + (size_t)(16 + c) * 32 + 8 * g;
        const float* pn = Wih1b + (size_t)(32 + c) * 32 + 8 * g;
#pragma unroll
        for (int e = 0; e < 8; ++e) {
            Abr[e] = (_Float16)pr[e];
            Abz[e] = (_Float16)pz[e];
            Abn[e] = (_Float16)pn[e];
        }
    }
    f4t Cbr, Cbz, Cbn;
    float ghn[4];
#pragma unroll
    for (int i = 0; i < 4; ++i) {
        const int row = 4 * g + i;
        Cbr[i] = bih1b[row] + bhh1b[row];
        Cbz[i] = bih1b[16 + row] + bhh1b[16 + row];
        Cbn[i] = bih1b[32 + row];
        ghn[i] = bhh1b[32 + row];
    }
    h8t By;
    { union { uint4 u; h8t h; } cv; cv.u = yfin; By = cv.h; }
    f4t Dr = __builtin_amdgcn_mfma_f32_16x16x32_f16(Abr, By, Cbr, 0, 0, 0);
    f4t Dz = __builtin_amdgcn_mfma_f32_16x16x32_f16(Abz, By, Cbz, 0, 0, 0);
    f4t Dn = __builtin_amdgcn_mfma_f32_16x16x32_f16(Abn, By, Cbn, 0, 0, 0);
#pragma unroll
    for (int i = 0; i < 4; ++i) {
        float r = sig_(Dr[i]);
        float z = sig_(Dz[i]);
        float n = tanh_(fmaf(r, ghn[i], Dn[i]));
        out[(size_t)b * 32 + 16 + 4 * g + i] = (1.0f - z) * n;
    }
}

extern "C" void kernel_launch(void* const* d_in, const int* in_sizes, int n_in,
                              void* d_out, int out_size, void* d_ws, size_t ws_size,
                              hipStream_t stream) {
    const float* x     = (const float*)d_in[0];
    const float* Wih0f = (const float*)d_in[1];
    const float* Whh0f = (const float*)d_in[2];
    const float* bih0f = (const float*)d_in[3];
    const float* bhh0f = (const float*)d_in[4];
    const float* Wih0b = (const float*)d_in[5];
    const float* Whh0b = (const float*)d_in[6];
    const float* bih0b = (const float*)d_in[7];
    const float* bhh0b = (const float*)d_in[8];
    const float* Wih1f = (const float*)d_in[9];
    const float* Whh1f = (const float*)d_in[10];
    const float* bih1f = (const float*)d_in[11];
    const float* bhh1f = (const float*)d_in[12];
    const float* Wih1b = (const float*)d_in[13];
    const float* bih1b = (const float*)d_in[15];
    const float* bhh1b = (const float*)d_in[16];

    __half* y0f = (__half*)d_ws;                   // [T,B,16] f16 = 64 MiB
    __half* y0b = y0f + (size_t)T * B * 16;        // [T,B,16] f16 = 64 MiB
    float* out = (float*)d_out;

    // K1: 8192 (seq,dir) units, 16 units/block -> 512 blocks.
    hipLaunchKernelGGL(k_l0, dim3(B * 2 / 16), dim3(256), 0, stream,
                       x, Wih0f, Whh0f, bih0f, bhh0f,
                       Wih0b, Whh0b, bih0b, bhh0b, y0f, y0b);
    // K2: 4096 seqs, 16 per wave -> 256 blocks.
    hipLaunchKernelGGL(k_l1m, dim3(B / 16), dim3(64), 0, stream,
                       y0f, y0b, Wih1f, Whh1f, bih1f, bhh1f,
                       Wih1b, bih1b, bhh1b, out);
}

// Round 12
// 278.902 us; speedup vs baseline: 1.3317x; 1.0220x over previous
//
#include <hip/hip_runtime.h>
#include <hip/hip_fp16.h>

typedef _Float16 v2h __attribute__((ext_vector_type(2)));
typedef _Float16 h4t __attribute__((ext_vector_type(4)));
typedef _Float16 h8t __attribute__((ext_vector_type(8)));
typedef float f4t __attribute__((ext_vector_type(4)));

static constexpr int T = 512;
static constexpr int B = 4096;

__device__ __forceinline__ float frcp_(float x) { return __builtin_amdgcn_rcpf(x); }
__device__ __forceinline__ float sig_(float x) { return frcp_(1.0f + __expf(-x)); }
__device__ __forceinline__ float tanh_(float x) { return 1.0f - 2.0f * frcp_(1.0f + __expf(2.0f * x)); }

// Compiler fence + scheduling barrier (same-wave LDS ops are in-order in HW).
#define WAVE_SYNC() do { asm volatile("" ::: "memory"); \
                         __builtin_amdgcn_wave_barrier(); \
                         asm volatile("" ::: "memory"); } while (0)

__device__ __forceinline__ v2h as_h2_(unsigned u) {
    union { unsigned u; v2h h; } c; c.u = u; return c.h;
}

// pack 4 floats -> h4t via two v_cvt_pkrtz
__device__ __forceinline__ h4t pack4_(float a, float b, float c, float d) {
    auto p0 = __builtin_amdgcn_cvt_pkrtz(a, b);   // __fp16 x2
    auto p1 = __builtin_amdgcn_cvt_pkrtz(c, d);
    union { struct { decltype(p0) a, b; } p; h4t h; } cv;
    cv.p.a = p0; cv.p.b = p1;
    return cv.h;
}

// ---------------- Kernel 1: layer-0 forward AND backward scans -------------
// tid = [s:3][dir:1][j:4]; 16-lane unit per (seq,dir); lane j owns gate rows
// j,16+j,32+j. f16 rework: h exchanged via LDS as f16 (32B/unit, 2xb128
// reads), gate dots via v_dot2_f32_f16 against f16 weight pairs (scalar f32
// accumulate, no unpack / no reduce-adds), single cvt feeds LDS + y-store.
__global__ void __launch_bounds__(256, 2) k_l0(
    const float* __restrict__ x,      // [B,T]
    const float* __restrict__ Wf, const float* __restrict__ Uf,
    const float* __restrict__ bif, const float* __restrict__ bhf,
    const float* __restrict__ Wb, const float* __restrict__ Ub,
    const float* __restrict__ bib, const float* __restrict__ bhb,
    __half* __restrict__ y0f,         // [T,B,16] f16
    __half* __restrict__ y0b)         // [T,B,16] f16
{
    __shared__ __half hbuf[256];      // 16 units x 16 f16 (32 B/unit)
    const int tid  = threadIdx.x;
    const int j    = tid & 15;
    const int dir  = (tid >> 4) & 1;
    const int s    = tid >> 5;
    const int unit = tid >> 4;
    const int b    = blockIdx.x * 8 + s;
    __half* hb = hbuf + unit * 16;

    const float* Wih = dir ? Wb : Wf;
    const float* Whh = dir ? Ub : Uf;
    const float* bih = dir ? bib : bif;
    const float* bhh = dir ? bhb : bhf;

    // f16-packed hh weight rows (k-pairs)
    v2h wr[8], wz[8], wn[8];
#pragma unroll
    for (int q = 0; q < 8; ++q) {
        wr[q] = (v2h){ (_Float16)Whh[j * 16 + 2 * q],
                       (_Float16)Whh[j * 16 + 2 * q + 1] };
        wz[q] = (v2h){ (_Float16)Whh[(16 + j) * 16 + 2 * q],
                       (_Float16)Whh[(16 + j) * 16 + 2 * q + 1] };
        wn[q] = (v2h){ (_Float16)Whh[(32 + j) * 16 + 2 * q],
                       (_Float16)Whh[(32 + j) * 16 + 2 * q + 1] };
    }
    const float wxr  = Wih[j], wxz = Wih[16 + j], wxn = Wih[32 + j];
    const float br   = bih[j] + bhh[j];
    const float bz   = bih[16 + j] + bhh[16 + j];
    const float bin_ = bih[32 + j];
    const float bhn  = bhh[32 + j];

    const int t0   = dir ? (T - 1) : 0;
    const int step = dir ? -1 : 1;
    const float* xp = x + (size_t)b * T + t0;
    __half* yp = (dir ? y0b : y0f) + ((size_t)t0 * B + b) * 16 + j;
    const ptrdiff_t ystep = (ptrdiff_t)step * B * 16;

    hb[j] = __half(0.0f);
    WAVE_SYNC();

    float xv = xp[0];
    float x1 = xp[step];
    const float* xq = xp + 2 * step;   // 2-deep prefetch
    float hj = 0.0f;

    for (int it = 0; it < T; ++it) {
        float x2 = *xq;
        if (it < T - 3) xq += step;
        // read full h (16 f16 = 2 x b128)
        const uint4* hp = reinterpret_cast<const uint4*>(hb);
        uint4 u0 = hp[0], u1 = hp[1];
        const unsigned hw[8] = { u0.x, u0.y, u0.z, u0.w, u1.x, u1.y, u1.z, u1.w };
        float ar = fmaf(xv, wxr, br);
        float az = fmaf(xv, wxz, bz);
        float hn = bhn;
#pragma unroll
        for (int q = 0; q < 8; ++q) {
            v2h hh = as_h2_(hw[q]);
            ar = __builtin_amdgcn_fdot2(hh, wr[q], ar, false);
            az = __builtin_amdgcn_fdot2(hh, wz[q], az, false);
            hn = __builtin_amdgcn_fdot2(hh, wn[q], hn, false);
        }
        float r = sig_(ar), z = sig_(az);
        float n = tanh_(fmaf(r, hn, fmaf(xv, wxn, bin_)));
        hj = fmaf(z, hj - n, n);            // (1-z)*n + z*h
        __half hf = __float2half(hj);
        *yp = hf;                           // global store (f16)
        yp += ystep;
        WAVE_SYNC();                        // reads above the write
        hb[j] = hf;                         // LDS publish (f16)
        WAVE_SYNC();                        // write before next-iter reads
        xv = x1; x1 = x2;
    }
}

// ---------------- Kernel 2: layer-1 via MFMA, 16 sequences per wave --------
// (unchanged from round 11 — proven 122 us)
__global__ void __launch_bounds__(64, 1) k_l1m(
    const __half* __restrict__ y0f, const __half* __restrict__ y0b,
    const float* __restrict__ Wih1, const float* __restrict__ Whh1,
    const float* __restrict__ bih1, const float* __restrict__ bhh1,
    const float* __restrict__ Wih1b,
    const float* __restrict__ bih1b, const float* __restrict__ bhh1b,
    float* __restrict__ out)              // [B,32]
{
    const int lane = threadIdx.x & 63;
    const int c = lane & 15;
    const int g = lane >> 4;
    const int b = blockIdx.x * 16 + c;

    h8t Air, Aiz, Ain;
    {
        const float* pr = Wih1 + (size_t)c * 32 + 8 * g;
        const float* pz = Wih1 + (size_t)(16 + c) * 32 + 8 * g;
        const float* pn = Wih1 + (size_t)(32 + c) * 32 + 8 * g;
#pragma unroll
        for (int e = 0; e < 8; ++e) {
            Air[e] = (_Float16)pr[e];
            Aiz[e] = (_Float16)pz[e];
            Ain[e] = (_Float16)pn[e];
        }
    }
    h4t Ahr, Ahz, Ahn;
    {
        const float* pr = Whh1 + (size_t)c * 16 + 4 * g;
        const float* pz = Whh1 + (size_t)(16 + c) * 16 + 4 * g;
        const float* pn = Whh1 + (size_t)(32 + c) * 16 + 4 * g;
#pragma unroll
        for (int e = 0; e < 4; ++e) {
            Ahr[e] = (_Float16)pr[e];
            Ahz[e] = (_Float16)pz[e];
            Ahn[e] = (_Float16)pn[e];
        }
    }
    f4t Crb, Czb, Cnb, Chn, Z4;
#pragma unroll
    for (int i = 0; i < 4; ++i) {
        const int row = 4 * g + i;
        Crb[i] = bih1[row] + bhh1[row];
        Czb[i] = bih1[16 + row] + bhh1[16 + row];
        Cnb[i] = bih1[32 + row];
        Chn[i] = bhh1[32 + row];
        Z4[i]  = 0.0f;
    }

    const __half* ysrc = (g < 2) ? y0f : y0b;
    const uint4* yp = reinterpret_cast<const uint4*>(
        ysrc + (size_t)b * 16 + (size_t)(g & 1) * 8);
    const size_t ystr = (size_t)B * 2;            // uint4 per time step

    uint4 buf[8];
#pragma unroll
    for (int i = 0; i < 8; ++i) buf[i] = yp[(size_t)i * ystr];

    float h[4] = {0.0f, 0.0f, 0.0f, 0.0f};
    h4t Bh = {};

#pragma unroll 8
    for (int it = 0; it < T; ++it) {
        uint4 ya = buf[it & 7];
        const size_t tn = (it + 8 < T) ? (size_t)(it + 8) : (size_t)(T - 1);
        buf[it & 7] = yp[tn * ystr];              // issue load for t+8
        h8t By;
        { union { uint4 u; h8t h; } cv; cv.u = ya; By = cv.h; }
        f4t Dr = __builtin_amdgcn_mfma_f32_16x16x32_f16(Air, By, Crb, 0, 0, 0);
        f4t Dz = __builtin_amdgcn_mfma_f32_16x16x32_f16(Aiz, By, Czb, 0, 0, 0);
        f4t Dn = __builtin_amdgcn_mfma_f32_16x16x32_f16(Ain, By, Cnb, 0, 0, 0);
        f4t Er = __builtin_amdgcn_mfma_f32_16x16x16f16(Ahr, Bh, Z4, 0, 0, 0);
        f4t Ez = __builtin_amdgcn_mfma_f32_16x16x16f16(Ahz, Bh, Z4, 0, 0, 0);
        f4t En = __builtin_amdgcn_mfma_f32_16x16x16f16(Ahn, Bh, Chn, 0, 0, 0);
#pragma unroll
        for (int i = 0; i < 4; ++i) {
            float r = sig_(Dr[i] + Er[i]);
            float z = sig_(Dz[i] + Ez[i]);
            float n = tanh_(fmaf(r, En[i], Dn[i]));
            h[i] = fmaf(z, h[i] - n, n);
        }
        Bh = pack4_(h[0], h[1], h[2], h[3]);
    }

#pragma unroll
    for (int i = 0; i < 4; ++i)
        out[(size_t)b * 32 + 4 * g + i] = h[i];

    // ---- L1 backward single step at t=T-1 from h=0.
    uint4 yfin = buf[(T - 1) & 7];
    h8t Abr, Abz, Abn;
    {
        const float* pr = Wih1b + (size_t)c * 32 + 8 * g;
        const float* pz = Wih1b + (size_t)(16 + c) * 32 + 8 * g;
        const float* pn = Wih1b + (size_t)(32 + c) * 32 + 8 * g;
#pragma unroll
        for (int e = 0; e < 8; ++e) {
            Abr[e] = (_Float16)pr[e];
            Abz[e] = (_Float16)pz[e];
            Abn[e] = (_Float16)pn[e];
        }
    }
    f4t Cbr, Cbz, Cbn;
    float ghn[4];
#pragma unroll
    for (int i = 0; i < 4; ++i) {
        const int row = 4 * g + i;
        Cbr[i] = bih1b[row] + bhh1b[row];
        Cbz[i] = bih1b[16 + row] + bhh1b[16 + row];
        Cbn[i] = bih1b[32 + row];
        ghn[i] = bhh1b[32 + row];
    }
    h8t By;
    { union { uint4 u; h8t h; } cv; cv.u = yfin; By = cv.h; }
    f4t Dr = __builtin_amdgcn_mfma_f32_16x16x32_f16(Abr, By, Cbr, 0, 0, 0);
    f4t Dz = __builtin_amdgcn_mfma_f32_16x16x32_f16(Abz, By, Cbz, 0, 0, 0);
    f4t Dn = __builtin_amdgcn_mfma_f32_16x16x32_f16(Abn, By, Cbn, 0, 0, 0);
#pragma unroll
    for (int i = 0; i < 4; ++i) {
        float r = sig_(Dr[i]);
        float z = sig_(Dz[i]);
        float n = tanh_(fmaf(r, ghn[i], Dn[i]));
        out[(size_t)b * 32 + 16 + 4 * g + i] = (1.0f - z) * n;
    }
}

extern "C" void kernel_launch(void* const* d_in, const int* in_sizes, int n_in,
                              void* d_out, int out_size, void* d_ws, size_t ws_size,
                              hipStream_t stream) {
    const float* x     = (const float*)d_in[0];
    const float* Wih0f = (const float*)d_in[1];
    const float* Whh0f = (const float*)d_in[2];
    const float* bih0f = (const float*)d_in[3];
    const float* bhh0f = (const float*)d_in[4];
    const float* Wih0b = (const float*)d_in[5];
    const float* Whh0b = (const float*)d_in[6];
    const float* bih0b = (const float*)d_in[7];
    const float* bhh0b = (const float*)d_in[8];
    const float* Wih1f = (const float*)d_in[9];
    const float* Whh1f = (const float*)d_in[10];
    const float* bih1f = (const float*)d_in[11];
    const float* bhh1f = (const float*)d_in[12];
    const float* Wih1b = (const float*)d_in[13];
    const float* bih1b = (const float*)d_in[15];
    const float* bhh1b = (const float*)d_in[16];

    __half* y0f = (__half*)d_ws;                   // [T,B,16] f16 = 64 MiB
    __half* y0b = y0f + (size_t)T * B * 16;        // [T,B,16] f16 = 64 MiB
    float* out = (float*)d_out;

    // K1: 8192 (seq,dir) units, 16 units/block -> 512 blocks.
    hipLaunchKernelGGL(k_l0, dim3(B * 2 / 16), dim3(256), 0, stream,
                       x, Wih0f, Whh0f, bih0f, bhh0f,
                       Wih0b, Whh0b, bih0b, bhh0b, y0f, y0b);
    // K2: 4096 seqs, 16 per wave -> 256 blocks.
    hipLaunchKernelGGL(k_l1m, dim3(B / 16), dim3(64), 0, stream,
                       y0f, y0b, Wih1f, Whh1f, bih1f, bhh1f,
                       Wih1b, bih1b, bhh1b, out);
}